// Round 1
// baseline (2585.229 us; speedup 1.0000x reference)
//
#include <hip/hip_runtime.h>

// ---------------------------------------------------------------------------
// Model: BN -> patchify -> embed -> all-pairs MLP_LN (correl) ->
//        pair-merge pyramid (xcorr, dim j, 8 steps) -> interleave(emb,cc) ->
//        appc MLP_LN -> pair-merge pyramid (xpath, dim p, 6 steps) -> 4-layer MLP head
// All fp32. E=100, HID=150, P=256, B=4.
//
// Structural tricks:
//  * correl first layer = U[i] + V[j] (precomputed 150-vecs) since input is a concat.
//  * every pair-merge step's input row o is 200 CONTIGUOUS floats at in + o*200,
//    so one generic kernel serves xcorr steps, appc, and xpath steps.
// ---------------------------------------------------------------------------

#define TILE 16
#define XT_STRIDE 204   // 16-row input tile, padded (204%32=12 -> <=2-way conflicts, 16B-aligned rows)
#define HT_STRIDE 156   // hidden tile stride   (156%32=28 -> <=2-way, 16B-aligned rows)
#define OUT_STRIDE 104  // out tile stride      (104%32=8  -> 2-way on LN passes)

// ---- phase 2 (150->100 matvec) + LayerNorm + store, shared by correl & generic ----
__device__ __forceinline__ void phase2_ln_store(
    const float* ht, float* out_lds, float* red,
    const float* __restrict__ w2, const float* __restrict__ b2,
    const float* __restrict__ gg, const float* __restrict__ bb,
    float* __restrict__ out, long row0)
{
  const int tid = threadIdx.x;
  // out_lds[row][e] = dot_{k<150}(ht[row][k], w2[e][k]) + b2[e]
  for (int oi = tid; oi < 100 * TILE; oi += 256) {
    int e = oi >> 4, row = oi & 15;
    const float* hrow = ht + row * HT_STRIDE;
    const float* w = w2 + e * 150;
    float a0 = 0.f, a1 = 0.f, a2 = 0.f, a3 = 0.f;
    for (int k = 0; k < 148; k += 4) {
      float4 h4 = *reinterpret_cast<const float4*>(hrow + k);
      float2 w0 = *reinterpret_cast<const float2*>(w + k);
      float2 w1v = *reinterpret_cast<const float2*>(w + k + 2);
      a0 += h4.x * w0.x; a1 += h4.y * w0.y;
      a2 += h4.z * w1v.x; a3 += h4.w * w1v.y;
    }
    a0 += hrow[148] * w[148];
    a1 += hrow[149] * w[149];
    out_lds[row * OUT_STRIDE + e] = a0 + a1 + a2 + a3 + b2[e];
  }
  __syncthreads();
  // LayerNorm over 100 feats: 16 groups of 16 lanes, two-pass (matches ref numerics)
  {
    int row = tid >> 4, sub = tid & 15;
    const float* orow = out_lds + row * OUT_STRIDE;
    float s = 0.f;
    for (int e = sub; e < 100; e += 16) s += orow[e];
    s += __shfl_xor(s, 8, 16); s += __shfl_xor(s, 4, 16);
    s += __shfl_xor(s, 2, 16); s += __shfl_xor(s, 1, 16);
    float mu = s * 0.01f;
    float v = 0.f;
    for (int e = sub; e < 100; e += 16) { float d = orow[e] - mu; v += d * d; }
    v += __shfl_xor(v, 8, 16); v += __shfl_xor(v, 4, 16);
    v += __shfl_xor(v, 2, 16); v += __shfl_xor(v, 1, 16);
    float rs = rsqrtf(v * 0.01f + 1e-5f);
    if (sub == 0) { red[row] = mu; red[16 + row] = rs; }
  }
  __syncthreads();
  for (int oi = tid; oi < 100 * TILE; oi += 256) {
    int row = oi / 100, e = oi % 100;
    float val = (out_lds[row * OUT_STRIDE + e] - red[row]) * red[16 + row] * gg[e] + bb[e];
    out[(row0 + row) * 100 + e] = val;
  }
}

// ---- generic: rows of 200 -> Linear(150)+ReLU -> Linear(100) -> LN ----
__global__ __launch_bounds__(256) void mlp_merge_kernel(
    const float* __restrict__ in, float* __restrict__ out,
    const float* __restrict__ w1, const float* __restrict__ b1,
    const float* __restrict__ w2, const float* __restrict__ b2,
    const float* __restrict__ gg, const float* __restrict__ bb)
{
  __shared__ __align__(16) float xt[TILE * XT_STRIDE];
  __shared__ __align__(16) float ht[TILE * HT_STRIDE];
  __shared__ float out_lds[TILE * OUT_STRIDE];
  __shared__ float red[32];
  const int tid = threadIdx.x;
  const long row0 = (long)blockIdx.x * TILE;
  const float* inb = in + row0 * 200;
  for (int idx = tid; idx < TILE * 200; idx += 256)
    xt[(idx / 200) * XT_STRIDE + (idx % 200)] = inb[idx];
  __syncthreads();
  // phase 1: h[row][t] = relu(dot_{k<200}(x[row][k], w1[t][k]) + b1[t])
  for (int oi = tid; oi < 150 * TILE; oi += 256) {
    int t = oi >> 4, row = oi & 15;
    const float* xr = xt + row * XT_STRIDE;
    const float* w = w1 + t * 200;
    float a0 = 0.f, a1 = 0.f, a2 = 0.f, a3 = 0.f;
    for (int k = 0; k < 200; k += 4) {
      float4 x4 = *reinterpret_cast<const float4*>(xr + k);
      float4 w4 = *reinterpret_cast<const float4*>(w + k);
      a0 += x4.x * w4.x; a1 += x4.y * w4.y;
      a2 += x4.z * w4.z; a3 += x4.w * w4.w;
    }
    ht[row * HT_STRIDE + t] = fmaxf(a0 + a1 + a2 + a3 + b1[t], 0.f);
  }
  __syncthreads();
  phase2_ln_store(ht, out_lds, red, w2, b2, gg, bb, out, row0);
}

// ---- correl: h[j][t] = relu(U[i][t] + V[j][t] + b1[t]), then phase2+LN ----
__global__ __launch_bounds__(256) void correl_kernel(
    const float* __restrict__ U, const float* __restrict__ V,
    const float* __restrict__ b1,
    const float* __restrict__ w2, const float* __restrict__ b2,
    const float* __restrict__ gg, const float* __restrict__ bb,
    float* __restrict__ out)
{
  __shared__ __align__(16) float ht[TILE * HT_STRIDE];
  __shared__ float u_lds[152];
  __shared__ float out_lds[TILE * OUT_STRIDE];
  __shared__ float red[32];
  const int tid = threadIdx.x;
  const int bi = blockIdx.y;            // b*256 + i
  const int j0 = blockIdx.x * TILE;
  const int b = bi >> 8;
  if (tid < 150) u_lds[tid] = U[(long)bi * 150 + tid] + b1[tid];
  __syncthreads();
  const float* vbase = V + ((long)(b * 256 + j0)) * 150;
  for (int idx = tid; idx < TILE * 150; idx += 256) {
    int jj = idx / 150, t = idx % 150;
    ht[jj * HT_STRIDE + t] = fmaxf(u_lds[t] + vbase[idx], 0.f);
  }
  __syncthreads();
  long row0 = (long)bi * 256 + j0;
  phase2_ln_store(ht, out_lds, red, w2, b2, gg, bb, out, row0);
}

// ---- BatchNorm2d (training) per-channel stats, folded to scale/shift ----
__global__ void bn_stats_kernel(const float* __restrict__ x,
    const float* __restrict__ bn_w, const float* __restrict__ bn_b,
    float* __restrict__ stats)
{
  __shared__ float s_sum[256], s_sq[256];
  const int c = blockIdx.x;
  const int tid = threadIdx.x;
  float s = 0.f, q = 0.f;
  for (int idx = tid; idx < 4 * 65536; idx += 256) {
    int b = idx >> 16, hw = idx & 65535;
    float v = x[(((long)(b * 3 + c)) << 16) + hw];
    s += v; q += v * v;
  }
  s_sum[tid] = s; s_sq[tid] = q;
  __syncthreads();
  for (int off = 128; off > 0; off >>= 1) {
    if (tid < off) { s_sum[tid] += s_sum[tid + off]; s_sq[tid] += s_sq[tid + off]; }
    __syncthreads();
  }
  if (tid == 0) {
    const float n = 262144.f;
    float mu = s_sum[0] / n;
    float var = s_sq[0] / n - mu * mu;   // biased var, matches ref
    float rs = rsqrtf(var + 1e-5f);
    float scale = rs * bn_w[c];
    stats[c] = scale;
    stats[4 + c] = bn_b[c] - mu * scale;
  }
}

// ---- patchify + patch-embedding + pos ----
__global__ __launch_bounds__(256) void embed_kernel(
    const float* __restrict__ x, const float* __restrict__ stats,
    const float* __restrict__ pe_w, const float* __restrict__ pe_b,
    const float* __restrict__ pos, float* __restrict__ emb)
{
  __shared__ __align__(16) float patch[768];
  const int tid = threadIdx.x;
  const int bp = blockIdx.x;            // b*256 + p
  const int b = bp >> 8, p = bp & 255;
  const int nhi = p >> 4, nwi = p & 15;
  for (int i = tid; i < 768; i += 256) {
    int ph = i / 48, rem = i % 48;
    int pw = rem / 3, c = rem % 3;
    float v = x[(((long)(b * 3 + c)) * 256 + (nhi * 16 + ph)) * 256 + (nwi * 16 + pw)];
    patch[i] = v * stats[c] + stats[4 + c];
  }
  __syncthreads();
  if (tid < 100) {
    const float* w = pe_w + tid * 768;
    float a0 = 0.f, a1 = 0.f, a2 = 0.f, a3 = 0.f;
    for (int k = 0; k < 768; k += 4) {
      float4 p4 = *reinterpret_cast<const float4*>(patch + k);
      float4 w4 = *reinterpret_cast<const float4*>(w + k);
      a0 += p4.x * w4.x; a1 += p4.y * w4.y;
      a2 += p4.z * w4.z; a3 += p4.w * w4.w;
    }
    emb[(long)bp * 100 + tid] = a0 + a1 + a2 + a3 + pe_b[tid] + pos[p * 100 + tid];
  }
}

// ---- U = W1[:, :100] @ emb, V = W1[:, 100:] @ emb (corr first layer split) ----
__global__ __launch_bounds__(256) void uv_kernel(
    const float* __restrict__ emb, const float* __restrict__ w1,
    float* __restrict__ U, float* __restrict__ V)
{
  __shared__ __align__(16) float e_lds[100];
  const int tid = threadIdx.x;
  const int bp = blockIdx.x;
  if (tid < 100) e_lds[tid] = emb[(long)bp * 100 + tid];
  __syncthreads();
  if (tid < 150) {
    const float* w = w1 + tid * 200;
    float a0 = 0.f, a1 = 0.f, c0 = 0.f, c1 = 0.f;
    for (int k = 0; k < 100; k += 2) {
      float2 e2 = *reinterpret_cast<const float2*>(e_lds + k);
      a0 += e2.x * w[k];       a1 += e2.y * w[k + 1];
      c0 += e2.x * w[100 + k]; c1 += e2.y * w[100 + k + 1];
    }
    U[(long)bp * 150 + tid] = a0 + a1;
    V[(long)bp * 150 + tid] = c0 + c1;
  }
}

// ---- interleave emb & cc into ec rows of 200 ----
__global__ void ec_kernel(const float* __restrict__ emb,
    const float* __restrict__ cc, float* __restrict__ ec)
{
  int g = blockIdx.x * 256 + threadIdx.x;
  if (g < 1024 * 100) {
    int o = g / 100, e = g % 100;
    ec[(long)o * 200 + 2 * e] = emb[g];
    ec[(long)o * 200 + 2 * e + 1] = cc[g];
  }
}

// ---- final 4-layer MLP head, one block per batch element ----
__global__ __launch_bounds__(256) void head_kernel(
    const float* __restrict__ cp,
    const float* __restrict__ w1, const float* __restrict__ b1,
    const float* __restrict__ w2, const float* __restrict__ b2,
    const float* __restrict__ w3, const float* __restrict__ b3,
    const float* __restrict__ w4, const float* __restrict__ b4,
    float* __restrict__ out)
{
  __shared__ float a0[400], a1[200], a2[100], a3[50];
  const int b = blockIdx.x, tid = threadIdx.x;
  for (int i = tid; i < 400; i += 256) a0[i] = cp[b * 400 + i];
  __syncthreads();
  if (tid < 200) {
    float s = b1[tid];
    const float* w = w1 + tid * 400;
    for (int k = 0; k < 400; ++k) s += a0[k] * w[k];
    a1[tid] = fmaxf(s, 0.f);
  }
  __syncthreads();
  if (tid < 100) {
    float s = b2[tid];
    const float* w = w2 + tid * 200;
    for (int k = 0; k < 200; ++k) s += a1[k] * w[k];
    a2[tid] = fmaxf(s, 0.f);
  }
  __syncthreads();
  if (tid < 50) {
    float s = b3[tid];
    const float* w = w3 + tid * 100;
    for (int k = 0; k < 100; ++k) s += a2[k] * w[k];
    a3[tid] = fmaxf(s, 0.f);
  }
  __syncthreads();
  if (tid < 5) {
    float s = b4[tid];
    const float* w = w4 + tid * 50;
    for (int k = 0; k < 50; ++k) s += a3[k] * w[k];
    out[b * 5 + tid] = s;
  }
}

extern "C" void kernel_launch(void* const* d_in, const int* in_sizes, int n_in,
                              void* d_out, int out_size, void* d_ws, size_t ws_size,
                              hipStream_t stream)
{
  const float* x    = (const float*)d_in[0];
  const float* bn_w = (const float*)d_in[1];
  const float* bn_b = (const float*)d_in[2];
  const float* pe_w = (const float*)d_in[3];
  const float* pe_b = (const float*)d_in[4];
  const float* pos  = (const float*)d_in[5];
  const float* cw1 = (const float*)d_in[6];
  const float* cb1 = (const float*)d_in[7];
  const float* cw2 = (const float*)d_in[8];
  const float* cb2 = (const float*)d_in[9];
  const float* cg  = (const float*)d_in[10];
  const float* cbe = (const float*)d_in[11];
  const float* xw1 = (const float*)d_in[12];
  const float* xb1 = (const float*)d_in[13];
  const float* xw2 = (const float*)d_in[14];
  const float* xb2 = (const float*)d_in[15];
  const float* xg  = (const float*)d_in[16];
  const float* xbe = (const float*)d_in[17];
  const float* aw1 = (const float*)d_in[18];
  const float* ab1 = (const float*)d_in[19];
  const float* aw2 = (const float*)d_in[20];
  const float* ab2 = (const float*)d_in[21];
  const float* ag  = (const float*)d_in[22];
  const float* abe = (const float*)d_in[23];
  const float* pw1 = (const float*)d_in[24];
  const float* pb1 = (const float*)d_in[25];
  const float* pw2 = (const float*)d_in[26];
  const float* pb2 = (const float*)d_in[27];
  const float* pg  = (const float*)d_in[28];
  const float* pbe = (const float*)d_in[29];
  const float* h1w = (const float*)d_in[30];
  const float* h1b = (const float*)d_in[31];
  const float* h2w = (const float*)d_in[32];
  const float* h2b = (const float*)d_in[33];
  const float* h3w = (const float*)d_in[34];
  const float* h3b = (const float*)d_in[35];
  const float* h4w = (const float*)d_in[36];
  const float* h4b = (const float*)d_in[37];

  // workspace layout (floats)
  const size_t OFF_STATS = 0;                       // 16
  const size_t OFF_EMB   = 16;                      // 1024*100
  const size_t OFF_U     = OFF_EMB + 102400;        // 1024*150
  const size_t OFF_V     = OFF_U + 153600;          // 1024*150
  const size_t OFF_EC    = OFF_V + 153600;          // 1024*200
  const size_t OFF_A     = OFF_EC + 204800;         // 262144*100
  const size_t OFF_B     = OFF_A + 26214400;        // 131072*100
  const size_t NEED = (OFF_B + 13107200) * sizeof(float);
  if (ws_size < NEED) return;   // workspace too small -> bail (validation will flag)

  float* ws    = (float*)d_ws;
  float* stats = ws + OFF_STATS;
  float* emb   = ws + OFF_EMB;
  float* U     = ws + OFF_U;
  float* V     = ws + OFF_V;
  float* ec    = ws + OFF_EC;
  float* A     = ws + OFF_A;
  float* B     = ws + OFF_B;

  bn_stats_kernel<<<3, 256, 0, stream>>>(x, bn_w, bn_b, stats);
  embed_kernel<<<1024, 256, 0, stream>>>(x, stats, pe_w, pe_b, pos, emb);
  uv_kernel<<<1024, 256, 0, stream>>>(emb, cw1, U, V);
  correl_kernel<<<dim3(16, 1024), 256, 0, stream>>>(U, V, cb1, cw2, cb2, cg, cbe, A);

  // xcorr pyramid: d 256 -> 1 (8 merge steps), rows = 1024 * half
  float* cur = A; float* nxt = B;
  int half = 128;
  for (int s = 0; s < 8; ++s) {
    int nrows = 1024 * half;
    mlp_merge_kernel<<<nrows / 16, 256, 0, stream>>>(cur, nxt, xw1, xb1, xw2, xb2, xg, xbe);
    float* t = cur; cur = nxt; nxt = t;
    half >>= 1;
  }
  // cc now in `cur` (== A), 1024 rows of 100

  ec_kernel<<<(102400 + 255) / 256, 256, 0, stream>>>(emb, cur, ec);
  mlp_merge_kernel<<<1024 / 16, 256, 0, stream>>>(ec, B, aw1, ab1, aw2, ab2, ag, abe); // ca -> B

  // xpath pyramid: p 256 -> 4 (6 merge steps), rows = 4 * half
  cur = B; nxt = A;
  half = 128;
  for (int s = 0; s < 6; ++s) {
    int nrows = 4 * half;
    mlp_merge_kernel<<<nrows / 16, 256, 0, stream>>>(cur, nxt, pw1, pb1, pw2, pb2, pg, pbe);
    float* t = cur; cur = nxt; nxt = t;
    half >>= 1;
  }
  // cp now in `cur` (== B), shape (4, 400)

  head_kernel<<<4, 256, 0, stream>>>(cur, h1w, h1b, h2w, h2b, h3w, h3b, h4w, h4b,
                                     (float*)d_out);
}